// Round 14
// baseline (146.720 us; speedup 1.0000x reference)
//
#include <hip/hip_runtime.h>
#include <math.h>

#define B_DIM 8
#define S_DIM 4096
#define D_DIM 1024
#define N_DIM 16
#define ROWS (B_DIM * S_DIM)          // 32768

#define CHUNK_L 32
#define WARM 64
#define STEPS (CHUNK_L + WARM)        // 96
#define NCHAIN (B_DIM * (S_DIM / CHUNK_L))   // 1024 chains

#define XB_BLOCKS (ROWS / 32)          // 1024 blocks, 32 rows (2 waves x 16)
#define CW_BLOCKS ((N_DIM * D_DIM) / 128)   // 128

typedef float f32x4 __attribute__((ext_vector_type(4)));
typedef int i32x4 __attribute__((ext_vector_type(4)));

__device__ __forceinline__ void gl_lds16(const float* g, float* l) {
    __builtin_amdgcn_global_load_lds(
        (const __attribute__((address_space(1))) void*)g,
        (__attribute__((address_space(3))) void*)l, 16, 0, 0);
}

__device__ __forceinline__ void mfma3(f32x4& acc, i32x4 ah, i32x4 al,
                                      i32x4 bh, i32x4 bl) {
    asm volatile(
        "s_nop 1\n\t"
        "v_mfma_f32_16x16x32_bf16 %0, %1, %3, %0\n\t"
        "v_mfma_f32_16x16x32_bf16 %0, %2, %3, %0\n\t"
        "v_mfma_f32_16x16x32_bf16 %0, %1, %4, %0"
        : "+v"(acc)
        : "v"(ah), "v"(al), "v"(bh), "v"(bl));
}

__device__ __forceinline__ void split1(float v, unsigned& h, unsigned& lo) {
    unsigned u = __float_as_uint(v);
    h = u >> 16;
    float fh = __uint_as_float(u & 0xFFFF0000u);
    lo = __float_as_uint(v - fh) >> 16;
}

// pack two f32x4 (8 k-values) into bf16 hi/lo MFMA operands (R13-proven).
__device__ __forceinline__ void pack8v(f32x4 a, f32x4 b, i32x4& hi, i32x4& lo) {
    unsigned h0, l0, h1, l1;
    split1(a[0], h0, l0); split1(a[1], h1, l1);
    hi[0] = (int)(h0 | (h1 << 16)); lo[0] = (int)(l0 | (l1 << 16));
    split1(a[2], h0, l0); split1(a[3], h1, l1);
    hi[1] = (int)(h0 | (h1 << 16)); lo[1] = (int)(l0 | (l1 << 16));
    split1(b[0], h0, l0); split1(b[1], h1, l1);
    hi[2] = (int)(h0 | (h1 << 16)); lo[2] = (int)(l0 | (l1 << 16));
    split1(b[2], h0, l0); split1(b[3], h1, l1);
    hi[3] = (int)(h0 | (h1 << 16)); lo[3] = (int)(l0 | (l1 << 16));
}

// stage 16 rows x 64 k of x into wave-private LDS (R13-proven, swizzle ^rr).
__device__ __forceinline__ void xb_stage(const float* __restrict__ x,
                                         float* dst, int row0w, int kt, int l) {
    const int lr = l >> 4, kb = l & 15;
#pragma unroll
    for (int i = 0; i < 4; ++i) {
        int rr = i * 4 + lr;
        const float* src = x + (size_t)(row0w + rr) * D_DIM + kt * 64 +
                           ((kb ^ rr) * 4);
        gl_lds16(src, dst + i * 256);
    }
}

// compute one kt from LDS + preloaded B fragments (R13-proven math).
__device__ __forceinline__ void xb_compute(const float* xsw, int l,
                                           i32x4 bh0, i32x4 bl0,
                                           i32x4 bh1, i32x4 bl1, f32x4& acc) {
    const int g = l >> 4, col = l & 15;
    {
        const int blk0 = g ^ col;
        const int blk1 = (4 + g) ^ col;
        f32x4 xa = *(const f32x4*)(xsw + col * 64 + blk0 * 4);
        f32x4 xv = *(const f32x4*)(xsw + col * 64 + blk1 * 4);
        i32x4 ah, al;
        pack8v(xa, xv, ah, al);
        mfma3(acc, ah, al, bh0, bl0);
    }
    {
        const int blk0 = (8 + g) ^ col;
        const int blk1 = (12 + g) ^ col;
        f32x4 xa = *(const f32x4*)(xsw + col * 64 + blk0 * 4);
        f32x4 xv = *(const f32x4*)(xsw + col * 64 + blk1 * 4);
        i32x4 ah, al;
        pack8v(xa, xv, ah, al);
        mfma3(acc, ah, al, bh1, bl1);
    }
}

// ---------------------------------------------------------------------------
// DIAGNOSTIC: pure m13-style streaming read of x (perfect coalescing, 8
// blocks/CU, 32 waves/CU). Measures this harness's achievable x-read floor.
// ---------------------------------------------------------------------------
__global__ __launch_bounds__(256) void k_diag(const float* __restrict__ x,
                                              float* __restrict__ dout) {
    const size_t g = blockIdx.x * 256 + threadIdx.x;
    const float4* xq = (const float4*)x;
    float4 s = {0.f, 0.f, 0.f, 0.f};
#pragma unroll
    for (int i = 0; i < 16; ++i) {
        float4 v = xq[(size_t)i * 524288 + g];
        s.x += v.x; s.y += v.y; s.z += v.z; s.w += v.w;
    }
    dout[g] = (s.x + s.y) + (s.z + s.w);
}

// ---------------------------------------------------------------------------
// k_prep: pre-pack B into bf16 hi/lo MFMA fragments (R13 loadB layout).
// Bf[kt][part][lane], part = {h(kq0), l(kq0), h(kq1), l(kq1)}; 64 KB.
// ---------------------------------------------------------------------------
__global__ __launch_bounds__(256) void k_prep(const float* __restrict__ Bm,
                                              i32x4* __restrict__ Bf) {
    int u = blockIdx.x * 256 + threadIdx.x;   // 0..1023
    int ktc = u >> 6, l = u & 63;
#pragma unroll
    for (int kq = 0; kq < 2; ++kq) {
        const float* bp = Bm +
            (size_t)(ktc * 64 + kq * 32 + 4 * (l >> 4)) * N_DIM + (l & 15);
        f32x4 ea, eb;
#pragma unroll
        for (int j = 0; j < 4; ++j) {
            ea[j] = bp[j * N_DIM];
            eb[j] = bp[(16 + j) * N_DIM];
        }
        i32x4 hi, lo;
        pack8v(ea, eb, hi, lo);
        Bf[(ktc * 4 + kq * 2 + 0) * 64 + l] = hi;
        Bf[(ktc * 4 + kq * 2 + 1) * 64 + l] = lo;
    }
}

// ---------------------------------------------------------------------------
// Kernel 1 (fused): blocks [0,1024): xb via MFMA, 32 rows/block (2 waves,
// wave-private 16-row tiles, no barriers). Triple-buffered gl_lds staging 2
// tiles ahead + B fragments 1 ahead; uniform counted vmcnt(8) (T4, never 0
// in loop). 4 blocks/CU = 8 waves/CU. blocks [1024,1152): CW = C@W^T.
// ---------------------------------------------------------------------------
__global__ __launch_bounds__(128) void k_xbcw(const float* __restrict__ x,
                                              const i32x4* __restrict__ Bf,
                                              float* __restrict__ xb,
                                              const float* __restrict__ C,
                                              const float* __restrict__ W,
                                              float* __restrict__ CW) {
    const int t = threadIdx.x;
    if (blockIdx.x >= XB_BLOCKS) {
        int u = (blockIdx.x - XB_BLOCKS) * 128 + t;
        int d = u >> 4;
        int n = u & 15;
        const float* crow = C + n * D_DIM;
        const float* wrow = W + (size_t)d * D_DIM;
        float acc = 0.f;
#pragma unroll 4
        for (int k = 0; k < D_DIM; k += 4) {
            float4 c4 = *(const float4*)(crow + k);
            float4 w4 = *(const float4*)(wrow + k);
            acc = fmaf(c4.x, w4.x, acc);
            acc = fmaf(c4.y, w4.y, acc);
            acc = fmaf(c4.z, w4.z, acc);
            acc = fmaf(c4.w, w4.w, acc);
        }
        CW[n * D_DIM + d] = acc;
        return;
    }
    __shared__ float xs[3][2][1024];       // 24 KB: 3 bufs x 2 waves
    const int l = t & 63;
    const int w = t >> 6;                  // 0..1
    const int row0w = blockIdx.x * 32 + w * 16;
    float* base = &xs[0][0][0] + w * 1024;

    f32x4 acc = {0.f, 0.f, 0.f, 0.f};

    // prologue: stage tiles 0,1; B(0)
    xb_stage(x, base + 0 * 2048, row0w, 0, l);
    xb_stage(x, base + 1 * 2048, row0w, 1, l);
    const i32x4* bfl = Bf + l;
    i32x4 ch0 = bfl[0 * 64], cl0 = bfl[1 * 64];
    i32x4 ch1 = bfl[2 * 64], cl1 = bfl[3 * 64];

    int rs = 0, wslot = 2;
#pragma unroll 2
    for (int kt = 0; kt < 14; ++kt) {
        xb_stage(x, base + wslot * 2048, row0w, kt + 2, l);
        const i32x4* bfn = Bf + (kt + 1) * 256 + l;
        i32x4 nh0 = bfn[0 * 64], nl0 = bfn[1 * 64];
        i32x4 nh1 = bfn[2 * 64], nl1 = bfn[3 * 64];
        __builtin_amdgcn_sched_barrier(0);
        asm volatile("s_waitcnt vmcnt(8)" ::: "memory");
        __builtin_amdgcn_sched_barrier(0);
        xb_compute(base + rs * 2048, l, ch0, cl0, ch1, cl1, acc);
        ch0 = nh0; cl0 = nl0; ch1 = nh1; cl1 = nl1;
        rs = (rs == 2) ? 0 : rs + 1;
        wslot = (wslot == 2) ? 0 : wslot + 1;
    }
    {   // kt = 14
        const i32x4* bfn = Bf + 15 * 256 + l;
        i32x4 nh0 = bfn[0 * 64], nl0 = bfn[1 * 64];
        i32x4 nh1 = bfn[2 * 64], nl1 = bfn[3 * 64];
        __builtin_amdgcn_sched_barrier(0);
        asm volatile("s_waitcnt vmcnt(4)" ::: "memory");
        __builtin_amdgcn_sched_barrier(0);
        xb_compute(base + rs * 2048, l, ch0, cl0, ch1, cl1, acc);
        ch0 = nh0; cl0 = nl0; ch1 = nh1; cl1 = nl1;
        rs = (rs == 2) ? 0 : rs + 1;
    }
    {   // kt = 15
        __builtin_amdgcn_sched_barrier(0);
        asm volatile("s_waitcnt vmcnt(0)" ::: "memory");
        __builtin_amdgcn_sched_barrier(0);
        xb_compute(base + rs * 2048, l, ch0, cl0, ch1, cl1, acc);
    }
    asm volatile("s_nop 7\n\ts_nop 7");

    const int g = l >> 4, col = l & 15;
#pragma unroll
    for (int reg = 0; reg < 4; ++reg)
        xb[(size_t)(row0w + g * 4 + reg) * N_DIM + col] = acc[reg];
}

// ---------------------------------------------------------------------------
// Kernel 2: chunked scan (round-6 proven, UNCHANGED)
// ---------------------------------------------------------------------------
__global__ __launch_bounds__(64) void k_scan(const float* __restrict__ xb,
                                             const float* __restrict__ A,
                                             float* __restrict__ hs) {
    const int tid = threadIdx.x;
    const int n = tid & 15;
    const int base4 = (tid & 48) * 4;

    const int chain = blockIdx.x * 4 + (tid >> 4);
    const int b = chain >> 7;
    const int chunk = chain & 127;
    const int t0 = chunk * CHUNK_L - WARM;

    float Ar[16];
#pragma unroll
    for (int m4 = 0; m4 < 16; m4 += 4) {
        float4 v = *(const float4*)(A + n * 16 + m4);
        Ar[m4 + 0] = v.x; Ar[m4 + 1] = v.y; Ar[m4 + 2] = v.z; Ar[m4 + 3] = v.w;
    }

    const float* xp = xb + (size_t)b * S_DIM * N_DIM + n;
    float* hp = hs + (size_t)b * S_DIM * N_DIM + n;

    float ring[8];
#pragma unroll
    for (int i = 0; i < 8; ++i) {
        int tt = t0 + i;
        ring[i] = (tt >= 0) ? xp[(size_t)tt * N_DIM] : 0.f;
    }

    float h = 0.f;
    for (int tr0 = 0; tr0 < STEPS; tr0 += 8) {
#pragma unroll
        for (int j = 0; j < 8; ++j) {
            const int tr = tr0 + j;
            const float xv = ring[j];
            const int hbits = __float_as_int(h);
            int hm[16];
#pragma unroll
            for (int m = 0; m < 16; ++m)
                hm[m] = __builtin_amdgcn_ds_bpermute(base4 + m * 4, hbits);
            float acc0 = xv, acc1 = 0.f;
#pragma unroll
            for (int m = 0; m < 8; ++m) {
                acc0 = fmaf(Ar[m], __int_as_float(hm[m]), acc0);
                acc1 = fmaf(Ar[m + 8], __int_as_float(hm[m + 8]), acc1);
            }
            float g = acc0 + acc1;
            float ax = fabsf(g);
            float e = __expf(2.f * ax);
            float tv = 1.f - 2.f / (e + 1.f);
            h = (g < 0.f) ? -tv : tv;
            if (tr >= WARM)
                hp[(size_t)(t0 + tr) * N_DIM] = h;
            int tt = t0 + tr + 8;
            if (tr + 8 < STEPS)
                ring[j] = (tt >= 0) ? xp[(size_t)tt * N_DIM] : 0.f;
        }
    }
}

// ---------------------------------------------------------------------------
// Kernel 3: out[r][d] = sum_n hs[r][n] * CW[n][d] + bias[d]  (round-1 proven)
// ---------------------------------------------------------------------------
__global__ __launch_bounds__(256) void k_out(const float* __restrict__ hs,
                                             const float* __restrict__ CW,
                                             const float* __restrict__ bias,
                                             float* __restrict__ out) {
    const int t = threadIdx.x;
    const int d0 = t * 4;
    const int row0 = blockIdx.x * 32;
    float4 cw[16];
#pragma unroll
    for (int nn = 0; nn < 16; ++nn)
        cw[nn] = *(const float4*)(CW + nn * D_DIM + d0);
    float4 b4 = *(const float4*)(bias + d0);

    for (int r = row0; r < row0 + 32; ++r) {
        const float4* hp = (const float4*)(hs + (size_t)r * N_DIM);
        float4 h0 = hp[0], h1 = hp[1], h2 = hp[2], h3 = hp[3];
        float hv[16] = {h0.x, h0.y, h0.z, h0.w, h1.x, h1.y, h1.z, h1.w,
                        h2.x, h2.y, h2.z, h2.w, h3.x, h3.y, h3.z, h3.w};
        float4 acc = b4;
#pragma unroll
        for (int nn = 0; nn < 16; ++nn) {
            acc.x = fmaf(hv[nn], cw[nn].x, acc.x);
            acc.y = fmaf(hv[nn], cw[nn].y, acc.y);
            acc.z = fmaf(hv[nn], cw[nn].z, acc.z);
            acc.w = fmaf(hv[nn], cw[nn].w, acc.w);
        }
        *(float4*)(out + (size_t)r * D_DIM + d0) = acc;
    }
}

// ---------------------------------------------------------------------------
extern "C" void kernel_launch(void* const* d_in, const int* in_sizes, int n_in,
                              void* d_out, int out_size, void* d_ws,
                              size_t ws_size, hipStream_t stream) {
    const float* x    = (const float*)d_in[0];   // [8,4096,1024]
    const float* A    = (const float*)d_in[1];   // [16,16]
    const float* Bm   = (const float*)d_in[2];   // [1024,16]
    const float* C    = (const float*)d_in[3];   // [16,1024]
    const float* W    = (const float*)d_in[4];   // [1024,1024]
    const float* bias = (const float*)d_in[5];   // [1024]
    float* out = (float*)d_out;

    float* ws = (float*)d_ws;
    float* xb   = ws;                          // 524288 floats
    float* hs   = ws + 524288;                 // 524288
    float* CW   = ws + 1048576;                // 16384
    i32x4* Bf   = (i32x4*)(ws + 1064960);      // 4096 i32x4 = 64 KB
    float* diag = ws + 1081344;                // 524288

    k_diag<<<dim3(2048), dim3(256), 0, stream>>>(x, diag);
    k_prep<<<dim3(4), dim3(256), 0, stream>>>(Bm, Bf);
    k_xbcw<<<dim3(XB_BLOCKS + CW_BLOCKS), dim3(128), 0, stream>>>(
        x, Bf, xb, C, W, CW);
    k_scan<<<dim3(NCHAIN / 4), dim3(64), 0, stream>>>(xb, A, hs);
    k_out<<<dim3(ROWS / 32), dim3(256), 0, stream>>>(hs, CW, bias, out);
}

// Round 15
// 123.197 us; speedup vs baseline: 1.1909x; 1.1909x over previous
//
#include <hip/hip_runtime.h>
#include <math.h>

#define B_DIM 8
#define S_DIM 4096
#define D_DIM 1024
#define N_DIM 16
#define ROWS (B_DIM * S_DIM)          // 32768

#define CHUNK_L 32
#define WARM 64
#define STEPS (CHUNK_L + WARM)        // 96
#define NCHAIN (B_DIM * (S_DIM / CHUNK_L))   // 1024 chains

#define XB_BLOCKS (ROWS / 32)          // 1024 blocks, 32 rows (2 waves x 16)
#define CW_BLOCKS ((N_DIM * D_DIM) / 128)   // 128

typedef float f32x4 __attribute__((ext_vector_type(4)));
typedef int i32x4 __attribute__((ext_vector_type(4)));

__device__ __forceinline__ void gl_lds16(const float* g, float* l) {
    __builtin_amdgcn_global_load_lds(
        (const __attribute__((address_space(1))) void*)g,
        (__attribute__((address_space(3))) void*)l, 16, 0, 0);
}

__device__ __forceinline__ void mfma3(f32x4& acc, i32x4 ah, i32x4 al,
                                      i32x4 bh, i32x4 bl) {
    asm volatile(
        "s_nop 1\n\t"
        "v_mfma_f32_16x16x32_bf16 %0, %1, %3, %0\n\t"
        "v_mfma_f32_16x16x32_bf16 %0, %2, %3, %0\n\t"
        "v_mfma_f32_16x16x32_bf16 %0, %1, %4, %0"
        : "+v"(acc)
        : "v"(ah), "v"(al), "v"(bh), "v"(bl));
}

__device__ __forceinline__ void split1(float v, unsigned& h, unsigned& lo) {
    unsigned u = __float_as_uint(v);
    h = u >> 16;
    float fh = __uint_as_float(u & 0xFFFF0000u);
    lo = __float_as_uint(v - fh) >> 16;
}

__device__ __forceinline__ void pack8v(f32x4 a, f32x4 b, i32x4& hi, i32x4& lo) {
    unsigned h0, l0, h1, l1;
    split1(a[0], h0, l0); split1(a[1], h1, l1);
    hi[0] = (int)(h0 | (h1 << 16)); lo[0] = (int)(l0 | (l1 << 16));
    split1(a[2], h0, l0); split1(a[3], h1, l1);
    hi[1] = (int)(h0 | (h1 << 16)); lo[1] = (int)(l0 | (l1 << 16));
    split1(b[0], h0, l0); split1(b[1], h1, l1);
    hi[2] = (int)(h0 | (h1 << 16)); lo[2] = (int)(l0 | (l1 << 16));
    split1(b[2], h0, l0); split1(b[3], h1, l1);
    hi[3] = (int)(h0 | (h1 << 16)); lo[3] = (int)(l0 | (l1 << 16));
}

// stage 16 rows x 64 k of x into wave-private LDS (R13-proven, swizzle ^rr).
__device__ __forceinline__ void xb_stage(const float* __restrict__ x,
                                         float* dst, int row0w, int kt, int l) {
    const int lr = l >> 4, kb = l & 15;
#pragma unroll
    for (int i = 0; i < 4; ++i) {
        int rr = i * 4 + lr;
        const float* src = x + (size_t)(row0w + rr) * D_DIM + kt * 64 +
                           ((kb ^ rr) * 4);
        gl_lds16(src, dst + i * 256);
    }
}

// compute one kt from LDS + preloaded B fragments (R13-proven math).
__device__ __forceinline__ void xb_compute(const float* xsw, int l,
                                           i32x4 bh0, i32x4 bl0,
                                           i32x4 bh1, i32x4 bl1, f32x4& acc) {
    const int g = l >> 4, col = l & 15;
    {
        const int blk0 = g ^ col;
        const int blk1 = (4 + g) ^ col;
        f32x4 xa = *(const f32x4*)(xsw + col * 64 + blk0 * 4);
        f32x4 xv = *(const f32x4*)(xsw + col * 64 + blk1 * 4);
        i32x4 ah, al;
        pack8v(xa, xv, ah, al);
        mfma3(acc, ah, al, bh0, bl0);
    }
    {
        const int blk0 = (8 + g) ^ col;
        const int blk1 = (12 + g) ^ col;
        f32x4 xa = *(const f32x4*)(xsw + col * 64 + blk0 * 4);
        f32x4 xv = *(const f32x4*)(xsw + col * 64 + blk1 * 4);
        i32x4 ah, al;
        pack8v(xa, xv, ah, al);
        mfma3(acc, ah, al, bh1, bl1);
    }
}

// ---------------------------------------------------------------------------
// k_prep: pre-pack B into bf16 hi/lo MFMA fragments. NEW LAYOUT: per (kt,
// lane) one contiguous 64B line: Bf[(kt*64+l)*4 + {h0,l0,h1,l1}].
// ---------------------------------------------------------------------------
__global__ __launch_bounds__(256) void k_prep(const float* __restrict__ Bm,
                                              i32x4* __restrict__ Bf) {
    int u = blockIdx.x * 256 + threadIdx.x;   // 0..1023
    int ktc = u >> 6, l = u & 63;
    int idx = (ktc * 64 + l) * 4;
#pragma unroll
    for (int kq = 0; kq < 2; ++kq) {
        const float* bp = Bm +
            (size_t)(ktc * 64 + kq * 32 + 4 * (l >> 4)) * N_DIM + (l & 15);
        f32x4 ea, eb;
#pragma unroll
        for (int j = 0; j < 4; ++j) {
            ea[j] = bp[j * N_DIM];
            eb[j] = bp[(16 + j) * N_DIM];
        }
        i32x4 hi, lo;
        pack8v(ea, eb, hi, lo);
        Bf[idx + kq * 2 + 0] = hi;
        Bf[idx + kq * 2 + 1] = lo;
    }
}

// ---------------------------------------------------------------------------
// Kernel 1 (fused): blocks [0,1024): xb via MFMA, 32 rows/block (2 waves,
// wave-private 16-row tiles, no barriers). 3-deep gl_lds staging AND 2-deep
// B-fragment prefetch (named regs, rule #20); uniform counted vmcnt(16)
// (= 2 stages + 2 B-packs in flight, T4 — never 0 in loop). Fixes R14's
// one-iteration B lead that exposed L2 latency every iter.
// blocks [1024,1152): CW = C@W^T (round-1 proven).
// ---------------------------------------------------------------------------
__global__ __launch_bounds__(128) void k_xbcw(const float* __restrict__ x,
                                              const i32x4* __restrict__ Bf,
                                              float* __restrict__ xb,
                                              const float* __restrict__ C,
                                              const float* __restrict__ W,
                                              float* __restrict__ CW) {
    const int t = threadIdx.x;
    if (blockIdx.x >= XB_BLOCKS) {
        int u = (blockIdx.x - XB_BLOCKS) * 128 + t;
        int d = u >> 4;
        int n = u & 15;
        const float* crow = C + n * D_DIM;
        const float* wrow = W + (size_t)d * D_DIM;
        float acc = 0.f;
#pragma unroll 4
        for (int k = 0; k < D_DIM; k += 4) {
            float4 c4 = *(const float4*)(crow + k);
            float4 w4 = *(const float4*)(wrow + k);
            acc = fmaf(c4.x, w4.x, acc);
            acc = fmaf(c4.y, w4.y, acc);
            acc = fmaf(c4.z, w4.z, acc);
            acc = fmaf(c4.w, w4.w, acc);
        }
        CW[n * D_DIM + d] = acc;
        return;
    }
    __shared__ float xs[3][2][1024];       // 24 KB: 3 bufs x 2 waves
    const int l = t & 63;
    const int w = t >> 6;                  // 0..1
    const int row0w = blockIdx.x * 32 + w * 16;
    float* base = &xs[0][0][0] + w * 1024;
    const i32x4* bfl = Bf + l * 4;         // lane's 64B line at kt=0

    f32x4 acc = {0.f, 0.f, 0.f, 0.f};

    // prologue: stage tiles 0,1; B(0) -> c, B(1) -> m   (FIFO: s0 s1 B0 B1)
    xb_stage(x, base + 0 * 2048, row0w, 0, l);
    xb_stage(x, base + 1 * 2048, row0w, 1, l);
    i32x4 c0 = bfl[0], c1 = bfl[1], c2 = bfl[2], c3 = bfl[3];
    i32x4 m0 = bfl[256], m1 = bfl[257], m2 = bfl[258], m3 = bfl[259];

    int rs = 0, wslot = 2;
#pragma unroll 2
    for (int kt = 0; kt < 14; ++kt) {
        xb_stage(x, base + wslot * 2048, row0w, kt + 2, l);
        const i32x4* bfn = bfl + (kt + 2) * 256;
        i32x4 p0 = bfn[0], p1 = bfn[1], p2 = bfn[2], p3 = bfn[3];
        __builtin_amdgcn_sched_barrier(0);
        asm volatile("s_waitcnt vmcnt(16)" ::: "memory");
        __builtin_amdgcn_sched_barrier(0);
        xb_compute(base + rs * 2048, l, c0, c1, c2, c3, acc);
        c0 = m0; c1 = m1; c2 = m2; c3 = m3;
        m0 = p0; m1 = p1; m2 = p2; m3 = p3;
        rs = (rs == 2) ? 0 : rs + 1;
        wslot = (wslot == 2) ? 0 : wslot + 1;
    }
    {   // kt = 14: stage(15)/B(15) still in flight (8 items)
        __builtin_amdgcn_sched_barrier(0);
        asm volatile("s_waitcnt vmcnt(8)" ::: "memory");
        __builtin_amdgcn_sched_barrier(0);
        xb_compute(base + rs * 2048, l, c0, c1, c2, c3, acc);
        c0 = m0; c1 = m1; c2 = m2; c3 = m3;
        rs = (rs == 2) ? 0 : rs + 1;
    }
    {   // kt = 15
        __builtin_amdgcn_sched_barrier(0);
        asm volatile("s_waitcnt vmcnt(0)" ::: "memory");
        __builtin_amdgcn_sched_barrier(0);
        xb_compute(base + rs * 2048, l, c0, c1, c2, c3, acc);
    }
    asm volatile("s_nop 7\n\ts_nop 7");

    const int g = l >> 4, col = l & 15;
#pragma unroll
    for (int reg = 0; reg < 4; ++reg)
        xb[(size_t)(row0w + g * 4 + reg) * N_DIM + col] = acc[reg];
}

// ---------------------------------------------------------------------------
// Kernel 2: chunked scan (round-6 proven, UNCHANGED)
// ---------------------------------------------------------------------------
__global__ __launch_bounds__(64) void k_scan(const float* __restrict__ xb,
                                             const float* __restrict__ A,
                                             float* __restrict__ hs) {
    const int tid = threadIdx.x;
    const int n = tid & 15;
    const int base4 = (tid & 48) * 4;

    const int chain = blockIdx.x * 4 + (tid >> 4);
    const int b = chain >> 7;
    const int chunk = chain & 127;
    const int t0 = chunk * CHUNK_L - WARM;

    float Ar[16];
#pragma unroll
    for (int m4 = 0; m4 < 16; m4 += 4) {
        float4 v = *(const float4*)(A + n * 16 + m4);
        Ar[m4 + 0] = v.x; Ar[m4 + 1] = v.y; Ar[m4 + 2] = v.z; Ar[m4 + 3] = v.w;
    }

    const float* xp = xb + (size_t)b * S_DIM * N_DIM + n;
    float* hp = hs + (size_t)b * S_DIM * N_DIM + n;

    float ring[8];
#pragma unroll
    for (int i = 0; i < 8; ++i) {
        int tt = t0 + i;
        ring[i] = (tt >= 0) ? xp[(size_t)tt * N_DIM] : 0.f;
    }

    float h = 0.f;
    for (int tr0 = 0; tr0 < STEPS; tr0 += 8) {
#pragma unroll
        for (int j = 0; j < 8; ++j) {
            const int tr = tr0 + j;
            const float xv = ring[j];
            const int hbits = __float_as_int(h);
            int hm[16];
#pragma unroll
            for (int m = 0; m < 16; ++m)
                hm[m] = __builtin_amdgcn_ds_bpermute(base4 + m * 4, hbits);
            float acc0 = xv, acc1 = 0.f;
#pragma unroll
            for (int m = 0; m < 8; ++m) {
                acc0 = fmaf(Ar[m], __int_as_float(hm[m]), acc0);
                acc1 = fmaf(Ar[m + 8], __int_as_float(hm[m + 8]), acc1);
            }
            float g = acc0 + acc1;
            float ax = fabsf(g);
            float e = __expf(2.f * ax);
            float tv = 1.f - 2.f / (e + 1.f);
            h = (g < 0.f) ? -tv : tv;
            if (tr >= WARM)
                hp[(size_t)(t0 + tr) * N_DIM] = h;
            int tt = t0 + tr + 8;
            if (tr + 8 < STEPS)
                ring[j] = (tt >= 0) ? xp[(size_t)tt * N_DIM] : 0.f;
        }
    }
}

// ---------------------------------------------------------------------------
// Kernel 3: out[r][d] = sum_n hs[r][n] * CW[n][d] + bias[d]  (round-1 proven)
// ---------------------------------------------------------------------------
__global__ __launch_bounds__(256) void k_out(const float* __restrict__ hs,
                                             const float* __restrict__ CW,
                                             const float* __restrict__ bias,
                                             float* __restrict__ out) {
    const int t = threadIdx.x;
    const int d0 = t * 4;
    const int row0 = blockIdx.x * 32;
    float4 cw[16];
#pragma unroll
    for (int nn = 0; nn < 16; ++nn)
        cw[nn] = *(const float4*)(CW + nn * D_DIM + d0);
    float4 b4 = *(const float4*)(bias + d0);

    for (int r = row0; r < row0 + 32; ++r) {
        const float4* hp = (const float4*)(hs + (size_t)r * N_DIM);
        float4 h0 = hp[0], h1 = hp[1], h2 = hp[2], h3 = hp[3];
        float hv[16] = {h0.x, h0.y, h0.z, h0.w, h1.x, h1.y, h1.z, h1.w,
                        h2.x, h2.y, h2.z, h2.w, h3.x, h3.y, h3.z, h3.w};
        float4 acc = b4;
#pragma unroll
        for (int nn = 0; nn < 16; ++nn) {
            acc.x = fmaf(hv[nn], cw[nn].x, acc.x);
            acc.y = fmaf(hv[nn], cw[nn].y, acc.y);
            acc.z = fmaf(hv[nn], cw[nn].z, acc.z);
            acc.w = fmaf(hv[nn], cw[nn].w, acc.w);
        }
        *(float4*)(out + (size_t)r * D_DIM + d0) = acc;
    }
}

// ---------------------------------------------------------------------------
extern "C" void kernel_launch(void* const* d_in, const int* in_sizes, int n_in,
                              void* d_out, int out_size, void* d_ws,
                              size_t ws_size, hipStream_t stream) {
    const float* x    = (const float*)d_in[0];   // [8,4096,1024]
    const float* A    = (const float*)d_in[1];   // [16,16]
    const float* Bm   = (const float*)d_in[2];   // [1024,16]
    const float* C    = (const float*)d_in[3];   // [16,1024]
    const float* W    = (const float*)d_in[4];   // [1024,1024]
    const float* bias = (const float*)d_in[5];   // [1024]
    float* out = (float*)d_out;

    float* ws = (float*)d_ws;
    float* xb = ws;                            // 524288 floats
    float* hs = ws + 524288;                   // 524288
    float* CW = ws + 1048576;                  // 16384
    i32x4* Bf = (i32x4*)(ws + 1064960);        // 4096 i32x4 = 64 KB

    k_prep<<<dim3(4), dim3(256), 0, stream>>>(Bm, Bf);
    k_xbcw<<<dim3(XB_BLOCKS + CW_BLOCKS), dim3(128), 0, stream>>>(
        x, Bf, xb, C, W, CW);
    k_scan<<<dim3(NCHAIN / 4), dim3(64), 0, stream>>>(xb, A, hs);
    k_out<<<dim3(ROWS / 32), dim3(256), 0, stream>>>(hs, CW, bias, out);
}